// Round 19
// baseline (85.957 us; speedup 1.0000x reference)
//
#include <hip/hip_runtime.h>
#include <hip/hip_bf16.h>
#include <stdint.h>

// RadianceNetwork: 256 independent channel MLPs, B=64.
//   x  = concat(ue[3], view[3], feat[128], nid[1])  -> [64, 135]
//   h1 = relu(x @ W1[c] + b1[c])                    -> [64, 256]
//   h2 = relu(h1 @ W2[c] + b2[c])                   -> [64, 256]
//   o  = h2 @ W3[c] + b3[c]                         -> [64, 816]
// OUTPUT: real components only, fp32 [64][256][408] (R0-R5 forensics).
//
// R16 (84us): 93 steps x ~2200cy each; waves wait ~80% of every step with
// 32KB in flight; W rows fetched in 512B slices (2-7 visits/row).
// R19: (1) tiles 32k x 256n fp32 (32KB): one DMA instr = 1KB FULLY
// CONTIGUOUS = complete W1/W2 row (those layers now perfectly sequential);
// (2) ring of 3 slots, issue AFTER barrier -> 2 tiles (64KB) outstanding
// through all compute (2x R16); (3) 16 waves = 16 n-tiles, MT=4 -> 45 fat
// steps instead of 93. Raw s_barrier + graduated counted vmcnt (T3/T4),
// never draining mid-chunk. L3 tail 48 cols: lane-guarded 12-lane DMA.
// LDS: h1 32K + {x|h2} 32K + ring 3x32K = 160 KB dynamic (full CU budget).

#define NCH    256
#define BATCH  64
#define MT     4      // 16-row m-tiles per wave (full batch)
#define IN_K   135
#define HID    256
#define OUTN   816
#define OUTS   408    // stored real components per (m, c)
#define XPITCHB 336   // bytes per x row (168 bf16; zero-padded k in [135,168))
#define HROWB   512   // bytes per h row (256 bf16, swizzled)
#define NWAVES 16
#define BLOCK  1024
#define SLOTB  32768  // 32 k-rows x 256 n-cols fp32
#define SMEM_BYTES (160 * 1024)

typedef __bf16 bf16x8 __attribute__((ext_vector_type(8)));
typedef float  f32x4  __attribute__((ext_vector_type(4)));
typedef const __attribute__((address_space(1))) void* gas_t;
typedef __attribute__((address_space(3))) void*       las_t;

// One N-chunk (256 or 48 cols) of one layer, k over KT 32-tiles.
// MFMA 16x16x32 bf16 (layouts HW-verified, m89):
//   A: row m=lane&15, k=(lane>>4)*8+i  (ds_read_b128 from shared h/x LDS)
//   B: col n=lane&15, same k           (ds_read_b32 from ring slot + cvt)
//   D: col n=lane&15, row m=(lane>>4)*4+r
// Ring slot (DMA, linear): fp32 [k 0..31][n 0..NCW-1], row pitch NCW*4.
// Wave w issues 2 instrs (k-rows 2w, 2w+1); lane l covers cols l*4..l*4+3
// (full chunks: 64 lanes = 1KB contiguous; 48-chunk: lanes 0-11 = 192B).
template<int K, int KT, int NSRC, int NCW, bool ASWZ, bool RELU>
__device__ __forceinline__ void chunk_pipe(
    const char*  __restrict__ A,     // LDS activations (x or swizzled h)
    const float* __restrict__ Wg,    // [K][NSRC] weights, channel base
    const float* __restrict__ bg,    // bias, channel base
    char*        __restrict__ Hout,  // LDS out (RELU), swizzled pitch 512B
    float*       __restrict__ Gout,  // global out base (+c*OUTS)
    unsigned long long out_sz, int nc0,
    char* __restrict__ wslots,       // 3 x 32 KB ring
    int wave, int lane)
{
  constexpr int PITCH = NCW * 4;     // slot row pitch (bytes)
  const int col = lane & 15;
  const int g   = lane >> 4;
  const bool active = (wave * 16) < NCW;

  // chunk entry: previous chunk's LDS reads/writes fully drained & published
  asm volatile("s_waitcnt lgkmcnt(0)" ::: "memory");
  asm volatile("s_barrier" ::: "memory");

  auto issue = [&](int t) {
    if (t < KT) {
      char* base = wslots + (t % 3) * SLOTB;
#pragma unroll
      for (int j = 0; j < 2; ++j) {
        const int r = 2 * wave + j;            // tile k-row 0..31
        int k = t * 32 + r;
        if (K % 32 != 0) k = (k < K) ? k : (K - 1);   // L1 tail: finite clamp
        const float* src = Wg + (size_t)k * NSRC + nc0 + (size_t)lane * 4;
        char* dst = base + r * PITCH;
        if (NCW == 256) {
          __builtin_amdgcn_global_load_lds((gas_t)src, (las_t)dst, 16, 0, 0);
        } else {
          if (lane * 4 < NCW)                  // 12 lanes: 192B, in-bounds
            __builtin_amdgcn_global_load_lds((gas_t)src, (las_t)dst, 16, 0, 0);
        }
      }
    }
  };

  issue(0); issue(1);                // 2 tiles (4 instrs) in flight

  f32x4 acc[MT] = {};

#pragma unroll
  for (int kt = 0; kt < KT; ++kt) {
    // tile kt landed when only tile kt+1's 2 instrs remain outstanding
    if (kt < KT - 1) asm volatile("s_waitcnt vmcnt(2)" ::: "memory");
    else             asm volatile("s_waitcnt vmcnt(0)" ::: "memory");
    asm volatile("s_barrier" ::: "memory");   // all waves' tile-kt landed;
                                              // all waves done with slot kt-1
    issue(kt + 2);                   // safe: overwrites slot (kt-1)%3

    if (active) {
      const char* slot = wslots + (kt % 3) * SLOTB;
      bf16x8 bfrag;
#pragma unroll
      for (int i = 0; i < 8; ++i) {
        const float w = *(const float*)(slot + (uint32_t)(g * 8 + i) * PITCH +
                                        (uint32_t)(wave * 16 + col) * 4u);
        bfrag[i] = (__bf16)w;
      }
      const int kb = kt * 32 + g * 8;
#pragma unroll
      for (int mt = 0; mt < MT; ++mt) {
        const int m = mt * 16 + col;
        const uint32_t ab = ASWZ
            ? (uint32_t)m * HROWB + (((uint32_t)(kb * 2)) ^ (((uint32_t)m & 7u) << 4))
            : (uint32_t)m * XPITCHB + (uint32_t)(kb * 2);
        const bf16x8 afrag = *(const bf16x8*)(A + ab);
        acc[mt] = __builtin_amdgcn_mfma_f32_16x16x32_bf16(afrag, bfrag, acc[mt], 0, 0, 0);
      }
    }
  }

  // epilogue: bias (+relu->LDS | even-col fp32->global)
  if (active) {
    const int n = nc0 + wave * 16 + col;
    const float bias = bg[n];
#pragma unroll
    for (int mt = 0; mt < MT; ++mt) {
#pragma unroll
      for (int r = 0; r < 4; ++r) {
        float v = acc[mt][r] + bias;
        const int m = mt * 16 + g * 4 + r;
        if (RELU) {
          v = v > 0.f ? v : 0.f;
          *(__bf16*)(Hout + (uint32_t)m * HROWB +
                     (((uint32_t)(n * 2)) ^ (((uint32_t)m & 7u) << 4))) = (__bf16)v;
        } else if ((n & 1) == 0) {           // real component only
          const unsigned long long oi =
              (unsigned long long)m * (NCH * OUTS) + (unsigned long long)(n >> 1);
          if (oi < out_sz) Gout[oi] = v;
        }
      }
    }
  }
}

__global__ __launch_bounds__(BLOCK) void radiance_mlp_kernel(
    const float* __restrict__ ue,   const float* __restrict__ view,
    const float* __restrict__ feat, const int*   __restrict__ ids,
    const float* __restrict__ W1, const float* __restrict__ b1,
    const float* __restrict__ W2, const float* __restrict__ b2,
    const float* __restrict__ W3, const float* __restrict__ b3,
    float* __restrict__ out, unsigned long long out_sz)
{
  extern __shared__ __attribute__((aligned(16))) char smem[];
  char* buf0   = smem;               // h1: 32 KB (swizzled pitch 512B)
  char* buf1   = smem + 32768;       // x (pitch 336B) then h2: 32 KB
  char* wslots = smem + 65536;       // 3 x 32 KB W ring

  const int c    = blockIdx.x;       // one full-batch block per channel
  const int tid  = threadIdx.x;
  const int wave = tid >> 6;
  const int lane = tid & 63;

  // Stage input x -> bf16 in buf1 (pitch 336B), zero-pad k in [135,168).
  for (int idx = tid; idx < BATCH * (XPITCHB / 2); idx += BLOCK) {
    const int m = idx / (XPITCHB / 2);
    const int k = idx - m * (XPITCHB / 2);
    float v = 0.0f;
    if (k < 3)         v = ue[m * 3 + k];
    else if (k < 6)    v = view[m * 3 + (k - 3)];
    else if (k < 134)  v = feat[m * 128 + (k - 6)];
    else if (k == 134) v = ((float)ids[m] - 1.0f) * (1.0f / 63.0f);
    *(__bf16*)(buf1 + (uint32_t)m * XPITCHB + 2u * (uint32_t)k) = (__bf16)v;
  }
  __syncthreads();

  // L1: x(buf1) -> h1(buf0).  K=135 (5 k-tiles), N=256 in ONE chunk.
  chunk_pipe<IN_K, 5, HID, 256, false, true>(
      buf1, W1 + (size_t)c * IN_K * HID, b1 + (size_t)c * HID,
      buf0, nullptr, 0, 0, wslots, wave, lane);

  // L2: h1(buf0) -> h2(buf1).  K=256 (8 k-tiles), N=256 in ONE chunk.
  chunk_pipe<HID, 8, HID, 256, true, true>(
      buf0, W2 + (size_t)c * HID * HID, b2 + (size_t)c * HID,
      buf1, nullptr, 0, 0, wslots, wave, lane);

  // L3: h2(buf1) -> out.  K=256, N=816 = 3 x 256 + 48.
  const float* W3c = W3 + (size_t)c * HID * OUTN;
  const float* b3c = b3 + (size_t)c * OUTN;
  float* outc = out + (size_t)c * OUTS;
  chunk_pipe<HID, 8, OUTN, 256, true, false>(buf1, W3c, b3c, nullptr, outc,
                                             out_sz, 0,   wslots, wave, lane);
  chunk_pipe<HID, 8, OUTN, 256, true, false>(buf1, W3c, b3c, nullptr, outc,
                                             out_sz, 256, wslots, wave, lane);
  chunk_pipe<HID, 8, OUTN, 256, true, false>(buf1, W3c, b3c, nullptr, outc,
                                             out_sz, 512, wslots, wave, lane);
  chunk_pipe<HID, 8, OUTN, 48, true, false>(buf1, W3c, b3c, nullptr, outc,
                                            out_sz, 768, wslots, wave, lane);
}

extern "C" void kernel_launch(void* const* d_in, const int* in_sizes, int n_in,
                              void* d_out, int out_size, void* d_ws, size_t ws_size,
                              hipStream_t stream) {
  const float* ue   = (const float*)d_in[0];
  const float* view = (const float*)d_in[1];
  const float* feat = (const float*)d_in[2];
  const int*   ids  = (const int*)d_in[3];
  const float* W1   = (const float*)d_in[4];
  const float* b1   = (const float*)d_in[5];
  const float* W2   = (const float*)d_in[6];
  const float* b2   = (const float*)d_in[7];
  const float* W3   = (const float*)d_in[8];
  const float* b3   = (const float*)d_in[9];
  float* out = (float*)d_out;

  // Host-side attribute set (not a stream op; graph-capture-safe, idempotent).
  hipFuncSetAttribute(reinterpret_cast<const void*>(radiance_mlp_kernel),
                      hipFuncAttributeMaxDynamicSharedMemorySize, SMEM_BYTES);

  hipLaunchKernelGGL(radiance_mlp_kernel, dim3(NCH), dim3(BLOCK), SMEM_BYTES,
                     stream, ue, view, feat, ids, W1, b1, W2, b2, W3, b3,
                     out, (unsigned long long)out_size);
}